// Round 1
// baseline (315.197 us; speedup 1.0000x reference)
//
#include <hip/hip_runtime.h>
#include <hip/hip_bf16.h>

// MetaNetImageEncoder on MI355X.
// Pipeline:
//  K1 patchify+cast:  x[64,3,224,224]f32 -> A_bf[64*256, 768] bf16 (rows 196..255 zero pad)
//  K2 transpose_cast: {W1,dW1[8],W2,dW2[8]} f32 [k][n] -> WT bf16 [mat][n][k]  (18 mats)
//  K3 gemm_pool (phase A, coefs=null): pooled_A = mean_n relu(A@W1 + b1)      -> bf16
//  K4 gemm2 (1 mat):   base = pooled_A@W2 + b2                                -> f32
//  K5 metanet:         coefs = relu(base@mw1+mb1)@mw2+mb2                     -> f32 [64,8]
//  K3 gemm_pool (phase B, coefs): pooled_B = mean_n relu(A@(W1+Σc dW1) + b1+c@db1)
//  K4 gemm2 (9 mats):  Y[j] = pooled_B @ {W2,dW2_t}                           -> f32
//  K6 combine:         out = Y0 + b2 + Σ_t c_t (Y[1+t] + db2_t)
//
// MFMA 16x16x32 bf16; verified layouts (learn_hip m89/m120):
//   A-frag: A[m=lane&15][k=(lane>>4)*8+j], B-frag: B[k=(lane>>4)*8+j][n=lane&15]
//   C/D:    col=lane&15, row=(lane>>4)*4+reg

typedef __bf16 bf16x8 __attribute__((ext_vector_type(8)));
typedef float f32x4 __attribute__((ext_vector_type(4)));

struct alignas(16) BF8 { __hip_bfloat16 h[8]; };

constexpr int BATCH = 64;
constexpr int NP    = 196;    // patches per image (14x14)
constexpr int NPAD  = 256;    // padded rows per sample
constexpr int DIM   = 768;
constexpr int NT    = 8;
constexpr int HM    = 192;
constexpr size_t MSZ = (size_t)DIM * DIM;   // 589824 elems per matrix

// ---------------- K1: patchify + cast to bf16, pad rows to 256 ----------------
__global__ void k_patchify(const float* __restrict__ x, __hip_bfloat16* __restrict__ A) {
  int idx  = blockIdx.x * blockDim.x + threadIdx.x;   // 16384 * 192
  int col4 = idx % (DIM / 4);
  int row  = idx / (DIM / 4);
  int d = col4 * 4;
  int b = row >> 8;
  int n = row & 255;
  __hip_bfloat16 tmp[4];
  if (n < NP) {
    int hp = n / 14, wp = n % 14;
    int c  = d >> 8;
    int rr = d & 255;
    int i = rr >> 4, j = rr & 15;    // j in {0,4,8,12} since d%4==0
    const float* src = x + ((((size_t)b * 3 + c) * 224 + hp * 16 + i) * 224 + wp * 16 + j);
    float4 f = *(const float4*)src;
    tmp[0] = __float2bfloat16(f.x);
    tmp[1] = __float2bfloat16(f.y);
    tmp[2] = __float2bfloat16(f.z);
    tmp[3] = __float2bfloat16(f.w);
  } else {
    tmp[0] = tmp[1] = tmp[2] = tmp[3] = __float2bfloat16(0.0f);
  }
  *(ushort4*)(A + (size_t)row * DIM + d) = *(ushort4*)tmp;
}

// ---------------- K2: transpose + cast weights: WT[mat][n][k] = W[mat][k][n] ----------------
__global__ void k_transpose_cast(const float* __restrict__ W1, const float* __restrict__ dW1,
                                 const float* __restrict__ W2, const float* __restrict__ dW2,
                                 __hip_bfloat16* __restrict__ WT) {
  __shared__ float tile[32][33];
  int mat = blockIdx.z;
  const float* src;
  if      (mat == 0) src = W1;
  else if (mat <= 8) src = dW1 + (size_t)(mat - 1) * MSZ;
  else if (mat == 9) src = W2;
  else               src = dW2 + (size_t)(mat - 10) * MSZ;
  int n0 = blockIdx.x * 32;
  int k0 = blockIdx.y * 32;
  int tx = threadIdx.x & 31, ty = threadIdx.x >> 5;
#pragma unroll
  for (int r = ty; r < 32; r += 8)
    tile[r][tx] = src[(size_t)(k0 + r) * DIM + n0 + tx];
  __syncthreads();
  __hip_bfloat16* dst = WT + (size_t)mat * MSZ;
#pragma unroll
  for (int r = ty; r < 32; r += 8)
    dst[(size_t)(n0 + r) * DIM + k0 + tx] = __float2bfloat16(tile[tx][r]);
}

// ---------------- K3: per-sample GEMM (mixed weights) + relu + masked column-mean ----------------
// block = (sample b, n-tile of 64). BM=256 (whole padded sample), BN=64, BK=32. 4 waves.
// wave w owns rows [w*64, w*64+64), all 64 cols.
constexpr int LDP = 40;  // LDS row stride in elements (32 + 8 pad -> 80B, 16B aligned)

__global__ __launch_bounds__(256, 2)
void k_gemm_pool(const __hip_bfloat16* __restrict__ A,   // [64*256, 768]
                 const __hip_bfloat16* __restrict__ WT,  // [18][768n][768k]
                 const float* __restrict__ b1,           // [768]
                 const float* __restrict__ db1,          // [8][768]
                 const float* __restrict__ coefs,        // [64][8] or null (phase A)
                 __hip_bfloat16* __restrict__ pooled) {  // [64][768]
  __shared__ __hip_bfloat16 Asl[256][LDP];
  __shared__ __hip_bfloat16 Bsl[64][LDP];
  __shared__ float biasl[64];
  __shared__ float cl[NT];
  __shared__ float red[4][64];

  int b  = blockIdx.x;
  int n0 = blockIdx.y * 64;
  int tid = threadIdx.x;

  if (tid < NT) cl[tid] = coefs ? coefs[b * NT + tid] : 0.0f;
  __syncthreads();
  if (tid < 64) {
    float bias = b1[n0 + tid];
    if (coefs) {
#pragma unroll
      for (int t = 0; t < NT; t++) bias += cl[t] * db1[t * DIM + n0 + tid];
    }
    biasl[tid] = bias;
  }

  int wave = tid >> 6, lane = tid & 63;
  int quad = lane >> 4, l16 = lane & 15;
  f32x4 acc[4][4] = {};   // [mfrag][nfrag]
  const __hip_bfloat16* Ag = A + (size_t)b * (NPAD * DIM);

  for (int k0 = 0; k0 < DIM; k0 += 32) {
    // ---- stage A tile: 256 rows x 32 k
    {
      int kl = (tid & 3) * 8;
      int r  = tid >> 2;
#pragma unroll
      for (int p = 0; p < 4; p++, r += 64)
        *(uint4*)(&Asl[r][kl]) = *(const uint4*)(Ag + (size_t)r * DIM + k0 + kl);
    }
    // ---- stage B tile with on-the-fly weight mixing: Bsl[n][k] = W1T + Σ c_t dW1T_t
    {
      int kl = (tid & 3) * 8;
      int nl = tid >> 2;   // 0..63
      const __hip_bfloat16* p0 = WT + (size_t)(n0 + nl) * DIM + k0 + kl;
      if (coefs) {
        BF8 w = *(const BF8*)p0;
        float m[8];
#pragma unroll
        for (int i = 0; i < 8; i++) m[i] = __bfloat162float(w.h[i]);
#pragma unroll
        for (int t = 0; t < NT; t++) {
          BF8 dv = *(const BF8*)(p0 + (size_t)(1 + t) * MSZ);
          float c = cl[t];
#pragma unroll
          for (int i = 0; i < 8; i++) m[i] += c * __bfloat162float(dv.h[i]);
        }
        BF8 o;
#pragma unroll
        for (int i = 0; i < 8; i++) o.h[i] = __float2bfloat16(m[i]);
        *(BF8*)(&Bsl[nl][kl]) = o;
      } else {
        *(uint4*)(&Bsl[nl][kl]) = *(const uint4*)p0;
      }
    }
    __syncthreads();
    // ---- MFMA: wave rows m0..m0+63, cols 0..63
    int m0 = wave * 64;
    bf16x8 af[4], bfr[4];
#pragma unroll
    for (int mf = 0; mf < 4; mf++)
      af[mf] = *(const bf16x8*)(&Asl[m0 + mf * 16 + l16][quad * 8]);
#pragma unroll
    for (int nf = 0; nf < 4; nf++)
      bfr[nf] = *(const bf16x8*)(&Bsl[nf * 16 + l16][quad * 8]);
#pragma unroll
    for (int mf = 0; mf < 4; mf++)
#pragma unroll
      for (int nf = 0; nf < 4; nf++)
        acc[mf][nf] = __builtin_amdgcn_mfma_f32_16x16x32_bf16(af[mf], bfr[nf], acc[mf][nf], 0, 0, 0);
    __syncthreads();
  }

  // ---- epilogue: relu(acc + bias), mask pad rows, column sums
  int m0 = wave * 64;
  float colsum[4];
#pragma unroll
  for (int nf = 0; nf < 4; nf++) {
    float bias = biasl[nf * 16 + l16];
    float s = 0.0f;
#pragma unroll
    for (int mf = 0; mf < 4; mf++) {
      int rowbase = m0 + mf * 16 + quad * 4;
#pragma unroll
      for (int r = 0; r < 4; r++) {
        if (rowbase + r < NP) s += fmaxf(acc[mf][nf][r] + bias, 0.0f);
      }
    }
    // butterfly across the 4 quads (lanes 16 apart hold same col)
    s += __shfl_xor(s, 16, 64);
    s += __shfl_xor(s, 32, 64);
    colsum[nf] = s;
  }
  if (lane < 16) {
#pragma unroll
    for (int nf = 0; nf < 4; nf++) red[wave][nf * 16 + lane] = colsum[nf];
  }
  __syncthreads();
  if (tid < 64) {
    float s = red[0][tid] + red[1][tid] + red[2][tid] + red[3][tid];
    pooled[(size_t)b * DIM + n0 + tid] = __float2bfloat16(s * (1.0f / 196.0f));
  }
}

// ---------------- K4: small GEMM, M=64: Y[mat] = pooled @ WT[matbase+mat] (+bias) ----------------
__global__ __launch_bounds__(256, 2)
void k_gemm2(const __hip_bfloat16* __restrict__ Abf,   // [64][768]
             const __hip_bfloat16* __restrict__ WT,    // mats
             int matbase,
             const float* __restrict__ bias,           // [768] or null
             float* __restrict__ Y) {                  // [nmat][64][768]
  __shared__ __hip_bfloat16 Asl[64][LDP];
  __shared__ __hip_bfloat16 Bsl[64][LDP];
  int n0  = blockIdx.x * 64;
  int mat = blockIdx.y;
  int tid = threadIdx.x, wave = tid >> 6, lane = tid & 63;
  int quad = lane >> 4, l16 = lane & 15;
  f32x4 acc[4] = {};
  const __hip_bfloat16* Wm = WT + (size_t)(matbase + mat) * MSZ;
  for (int k0 = 0; k0 < DIM; k0 += 32) {
    int kl = (tid & 3) * 8;
    int r  = tid >> 2;
    *(uint4*)(&Asl[r][kl]) = *(const uint4*)(Abf + (size_t)r * DIM + k0 + kl);
    *(uint4*)(&Bsl[r][kl]) = *(const uint4*)(Wm + (size_t)(n0 + r) * DIM + k0 + kl);
    __syncthreads();
    bf16x8 bfr = *(const bf16x8*)(&Bsl[wave * 16 + l16][quad * 8]);
#pragma unroll
    for (int mf = 0; mf < 4; mf++) {
      bf16x8 af = *(const bf16x8*)(&Asl[mf * 16 + l16][quad * 8]);
      acc[mf] = __builtin_amdgcn_mfma_f32_16x16x32_bf16(af, bfr, acc[mf], 0, 0, 0);
    }
    __syncthreads();
  }
#pragma unroll
  for (int mf = 0; mf < 4; mf++) {
#pragma unroll
    for (int r = 0; r < 4; r++) {
      int row = mf * 16 + quad * 4 + r;
      int col = n0 + wave * 16 + l16;
      float v = acc[mf][r];
      if (bias) v += bias[col];
      Y[((size_t)mat * 64 + row) * DIM + col] = v;
    }
  }
}

// ---------------- K5: MetaNet: coefs = relu(base@mw1+mb1)@mw2 + mb2 ----------------
__global__ void k_metanet(const float* __restrict__ base,  // [64][768]
                          const float* __restrict__ mw1, const float* __restrict__ mb1,
                          const float* __restrict__ mw2, const float* __restrict__ mb2,
                          float* __restrict__ coefs) {     // [64][8]
  __shared__ float bl[DIM];
  __shared__ float hl[HM];
  int b = blockIdx.x, tid = threadIdx.x;   // 192 threads
  for (int i = tid; i < DIM; i += HM) bl[i] = base[(size_t)b * DIM + i];
  __syncthreads();
  float s = mb1[tid];
  for (int k = 0; k < DIM; k++) s += bl[k] * mw1[(size_t)k * HM + tid];
  hl[tid] = fmaxf(s, 0.0f);
  __syncthreads();
  if (tid < NT) {
    float c = mb2[tid];
    for (int j = 0; j < HM; j++) c += hl[j] * mw2[(size_t)j * NT + tid];
    coefs[b * NT + tid] = c;
  }
}

// ---------------- K6: combine: out = Y0 + b2 + Σ c_t (Y[1+t] + db2_t) ----------------
__global__ void k_combine(const float* __restrict__ Y,      // [9][64][768]
                          const float* __restrict__ coefs,  // [64][8]
                          const float* __restrict__ b2,     // [768]
                          const float* __restrict__ db2,    // [8][768]
                          float* __restrict__ out) {        // [64][768]
  int idx = blockIdx.x * 256 + threadIdx.x;   // 49152
  int b = idx / DIM, e = idx % DIM;
  float v = Y[(size_t)b * DIM + e] + b2[e];
#pragma unroll
  for (int t = 0; t < NT; t++) {
    float c = coefs[b * NT + t];
    v += c * (Y[((size_t)(1 + t) * 64 + b) * DIM + e] + db2[(size_t)t * DIM + e]);
  }
  out[idx] = v;
}

extern "C" void kernel_launch(void* const* d_in, const int* in_sizes, int n_in,
                              void* d_out, int out_size, void* d_ws, size_t ws_size,
                              hipStream_t stream) {
  const float* x   = (const float*)d_in[0];
  const float* W1  = (const float*)d_in[1];
  const float* b1  = (const float*)d_in[2];
  const float* W2  = (const float*)d_in[3];
  const float* b2  = (const float*)d_in[4];
  const float* dW1 = (const float*)d_in[5];
  const float* db1 = (const float*)d_in[6];
  const float* dW2 = (const float*)d_in[7];
  const float* db2 = (const float*)d_in[8];
  const float* mw1 = (const float*)d_in[9];
  const float* mb1 = (const float*)d_in[10];
  const float* mw2 = (const float*)d_in[11];
  const float* mb2 = (const float*)d_in[12];
  float* out = (float*)d_out;

  // workspace layout (bytes, 256-aligned); total ~48.6 MB
  char* ws = (char*)d_ws;
  __hip_bfloat16* A_bf     = (__hip_bfloat16*)(ws);                      // 25,165,824
  __hip_bfloat16* WT       = (__hip_bfloat16*)(ws + 25165824);           // 21,233,664
  __hip_bfloat16* pooledA  = (__hip_bfloat16*)(ws + 46399488);           //     98,304
  float*          base     = (float*)         (ws + 46497792);           //    196,608
  float*          coefs    = (float*)         (ws + 46694400);           //      2,048
  __hip_bfloat16* pooledB  = (__hip_bfloat16*)(ws + 46696448);           //     98,304
  float*          Y        = (float*)         (ws + 46794752);           //  1,769,472
  (void)ws_size; (void)in_sizes; (void)n_in; (void)out_size;

  // K1: patchify + cast (zero-fills pad rows every call; ws is re-poisoned by harness)
  k_patchify<<<dim3((BATCH * NPAD * (DIM / 4)) / 256), 256, 0, stream>>>(x, A_bf);
  // K2: weight transpose+cast (18 matrices)
  k_transpose_cast<<<dim3(24, 24, 18), 256, 0, stream>>>(W1, dW1, W2, dW2, WT);
  // K3 phase A
  k_gemm_pool<<<dim3(BATCH, DIM / 64), 256, 0, stream>>>(A_bf, WT, b1, db1, nullptr, pooledA);
  // K4: base = pooled_A @ W2 + b2   (mat 9)
  k_gemm2<<<dim3(DIM / 64, 1), 256, 0, stream>>>(pooledA, WT, 9, b2, base);
  // K5: metanet -> coefs
  k_metanet<<<dim3(BATCH), HM, 0, stream>>>(base, mw1, mb1, mw2, mb2, coefs);
  // K3 phase B (mixed weights)
  k_gemm_pool<<<dim3(BATCH, DIM / 64), 256, 0, stream>>>(A_bf, WT, b1, db1, coefs, pooledB);
  // K4: Y[0..8] = pooled_B @ {W2, dW2_t}  (mats 9..17)
  k_gemm2<<<dim3(DIM / 64, 9), 256, 0, stream>>>(pooledB, WT, 9, nullptr, Y);
  // K6: combine
  k_combine<<<dim3((BATCH * DIM) / 256), 256, 0, stream>>>(Y, coefs, b2, db2, out);
}